// Round 4
// baseline (2175.106 us; speedup 1.0000x reference)
//
#include <hip/hip_runtime.h>
#include <cstdint>
#include <cstddef>

// Problem constants
#define B_  4096
#define H_  300
#define T_  43
#define NC_ 80
#define HP  320      // padded hidden/input dim (300 -> 320)
#define ND  1280     // padded 4H per direction
#define NDD 2560     // both directions
#define TR  304      // hs per-t row length in f16 (300 + 4 zero pad)
#define SB2 (T_ * TR) // hs per-(d,b) stride in f16 = 13072
#define XZC 4        // xz precompute chunk (timesteps)

typedef _Float16 f16;
typedef _Float16 half8 __attribute__((ext_vector_type(8)));
typedef _Float16 half4 __attribute__((ext_vector_type(4)));
typedef float    f32x4 __attribute__((ext_vector_type(4)));

__device__ __forceinline__ void gl_lds16(const void* g, void* l) {
  __builtin_amdgcn_global_load_lds(
      (const __attribute__((address_space(1))) void*)g,
      (__attribute__((address_space(3))) void*)l, 16, 0, 0);
}
__device__ __forceinline__ float sigmoid_(float x) {
  return 1.f / (1.f + __expf(-x));
}
__device__ __forceinline__ float tanh_fast(float x) {
  x = fminf(fmaxf(x, -15.f), 15.f);
  float e = __expf(2.f * x);
  return (e - 1.f) / (e + 1.f);
}

// ---------------------------------------------------------------------------
// Weight packing. Row index = d*1280 + 4*jh + g (gate-interleaved, i,f,g,o).
// Wih[2560][320], Whh[2560][320] (k>=300 zero -> makes garbage k-reads safe),
// bias[2560].
// ---------------------------------------------------------------------------
__global__ void prep_weights(const float* __restrict__ w_ih,
                             const float* __restrict__ w_hh,
                             const float* __restrict__ b_ih,
                             const float* __restrict__ b_hh,
                             f16* __restrict__ Wih, f16* __restrict__ Whh,
                             float* __restrict__ bias) {
  int idx = blockIdx.x * 256 + threadIdx.x;
  const int total = NDD * HP;
  if (idx < 2 * total) {
    int which = idx / total;  // 0 = Wih, 1 = Whh
    int rem = idx % total;
    int row = rem / HP, k = rem % HP;
    int d = row / ND, n = row % ND;
    int jh = n >> 2, g = n & 3;
    float v = 0.f;
    if (jh < H_ && k < H_) {
      const float* W = which ? w_hh : w_ih;
      v = W[((size_t)d * 4 * H_ + g * H_ + jh) * H_ + k];
    }
    (which ? Whh : Wih)[(size_t)row * HP + k] = (f16)v;
  }
  if (idx < NDD) {
    int d = idx / ND, n = idx % ND;
    int jh = n >> 2, g = n & 3;
    float v = 0.f;
    if (jh < H_)
      v = b_ih[d * 4 * H_ + g * H_ + jh] + b_hh[d * 4 * H_ + g * H_ + jh];
    bias[idx] = v;
  }
}

// ---------------------------------------------------------------------------
// x [B,H,T] fp32 -> xT[t*B+b][k] f16, k padded to 320 with zeros.
// ---------------------------------------------------------------------------
__global__ void prep_xT(const float* __restrict__ x, f16* __restrict__ xT) {
  __shared__ float tile[64][44];
  int b = blockIdx.x, ch = blockIdx.y;
  int h0 = ch * 64;
  for (int idx = threadIdx.x; idx < 64 * T_; idx += 256) {
    int hh = idx / T_, t = idx % T_;
    float v = 0.f;
    if (h0 + hh < H_) v = x[((size_t)b * H_ + h0 + hh) * T_ + t];
    tile[hh][t] = v;
  }
  __syncthreads();
  for (int idx = threadIdx.x; idx < 64 * T_; idx += 256) {
    int t = idx / 64, hh = idx % 64;
    xT[((size_t)t * B_ + b) * HP + h0 + hh] = (f16)tile[hh][t];
  }
}

// ---------------------------------------------------------------------------
// Precompute xz, z^T orientation, half4-gate-packed:
//   xz4[((tl*2 + d)*HP + jh)*B + b] = {z_i, z_f, z_g, z_o}
// A = Wih rows, B = xT rows. K = 320. Double-buffered 1-barrier K-loop.
// ---------------------------------------------------------------------------
__global__ void xz_gemm(const f16* __restrict__ Xc,   // [cn*B][320]
                        const f16* __restrict__ Wih,  // [2560][320]
                        half4* __restrict__ xz4) {
  __shared__ __attribute__((aligned(16))) f16 As[2][4096];
  __shared__ __attribute__((aligned(16))) f16 Bs[2][4096];
  const int tid = threadIdx.x;
  const int wave = tid >> 6, lane = tid & 63;
  const int mt = blockIdx.x, nt = blockIdx.y;
  const int lrow4 = lane >> 2, col8 = (lane & 3) << 3;
  const int wm = wave & 1, wn = wave >> 1;
  const int lr = lane & 15, lq = lane >> 4;
  const int kq = lq << 3;

  const f16* Ab = Wih + (size_t)nt * 128 * HP;
  const f16* Bb = Xc + (size_t)mt * 128 * HP;

  f32x4 acc[4][4];
#pragma unroll
  for (int i = 0; i < 4; i++)
#pragma unroll
    for (int j = 0; j < 4; j++) acc[i][j] = (f32x4){0.f, 0.f, 0.f, 0.f};

  // prologue: stage kt=0 into buf 0
#pragma unroll
  for (int i2 = 0; i2 < 2; i2++) {
    int r0 = wave * 32 + i2 * 16;
    gl_lds16(Ab + (size_t)(r0 + lrow4) * HP + col8, &As[0][r0 * 32]);
    gl_lds16(Bb + (size_t)(r0 + lrow4) * HP + col8, &Bs[0][r0 * 32]);
  }
  __syncthreads();

  for (int kt = 0; kt < HP / 32; ++kt) {
    const int cur = kt & 1;
    if (kt + 1 < HP / 32) {  // stage next tile; overlaps with compute below
      const int nk = (kt + 1) * 32;
#pragma unroll
      for (int i2 = 0; i2 < 2; i2++) {
        int r0 = wave * 32 + i2 * 16;
        gl_lds16(Ab + (size_t)(r0 + lrow4) * HP + nk + col8, &As[cur ^ 1][r0 * 32]);
        gl_lds16(Bb + (size_t)(r0 + lrow4) * HP + nk + col8, &Bs[cur ^ 1][r0 * 32]);
      }
    }
    half8 af[4], bf[4];
#pragma unroll
    for (int i = 0; i < 4; i++) {
      af[i] = *(const half8*)&As[cur][(wm * 64 + i * 16 + lr) * 32 + kq];
      bf[i] = *(const half8*)&Bs[cur][(wn * 64 + i * 16 + lr) * 32 + kq];
    }
#pragma unroll
    for (int i = 0; i < 4; i++)
#pragma unroll
      for (int j = 0; j < 4; j++)
        acc[i][j] = __builtin_amdgcn_mfma_f32_16x16x32_f16(af[i], bf[j],
                                                           acc[i][j], 0, 0, 0);
    __syncthreads();  // reads of buf[cur] done + next loads landed
  }

  const int dt = nt / 10;
  const int tl = mt >> 5;
#pragma unroll
  for (int i = 0; i < 4; i++) {
    const int jh = (nt % 10) * 32 + wm * 16 + i * 4 + lq;
    if (jh >= H_) continue;
#pragma unroll
    for (int j = 0; j < 4; j++) {
      const int b = (mt & 31) * 128 + wn * 64 + j * 16 + lr;
      half4 o;
#pragma unroll
      for (int r = 0; r < 4; r++) o[r] = (f16)acc[i][j][r];
      xz4[((size_t)(tl * 2 + dt) * HP + jh) * B_ + b] = o;
    }
  }
}

// ---------------------------------------------------------------------------
// One LSTM step, z^T orientation, double-buffered 1-barrier K-loop.
// h_prev is read straight out of hs (row t-1; stride bstride). k=300..319
// reads hit zero-padded / neighboring finite data x zero Whh columns -> safe.
// Writes only hs row t (via LDS transpose, coalesced half8).
// grid (10 jh-tiles, 32 b-tiles, 2 dirs), 256 thr.
// ---------------------------------------------------------------------------
__global__ void lstm_step(const f16* __restrict__ hprev,  // zbuf or hs+(t-1)*TR
                          long bstride, long dstride,     // f16 elements
                          float* __restrict__ c,          // [2][300][B]
                          const f16* __restrict__ Whh,    // [2560][320]
                          const float* __restrict__ bias, // [2560]
                          const half4* __restrict__ xz4,  // [2][320][B] packed
                          f16* __restrict__ hs,           // [2][B][43][304]
                          int t)
{
  __shared__ __attribute__((aligned(16))) f16 As[2][4096];
  __shared__ __attribute__((aligned(16))) f16 Bs[2][4096];
  f16* tile = &As[0][0];  // 32 x 136 f16, reused after GEMM

  const int tid = threadIdx.x;
  const int wave = tid >> 6, lane = tid & 63;
  const int wt = blockIdx.x, bt = blockIdx.y, d = blockIdx.z;
  const int lrow4 = lane >> 2, col8 = (lane & 3) << 3;
  const int wm = wave & 1, wn = wave >> 1;
  const int lr = lane & 15, lq = lane >> 4;
  const int kq = lq << 3;

  const f16* Wb = Whh + ((size_t)d * ND + wt * 128) * HP;
  const f16* hb = hprev + (size_t)d * dstride + (size_t)(bt * 128) * bstride;

  f32x4 acc[4][4];
#pragma unroll
  for (int i = 0; i < 4; i++)
#pragma unroll
    for (int j = 0; j < 4; j++) acc[i][j] = (f32x4){0.f, 0.f, 0.f, 0.f};

  // prologue: stage kt=0 into buf 0
#pragma unroll
  for (int i2 = 0; i2 < 2; i2++) {
    int r0 = wave * 32 + i2 * 16;
    gl_lds16(Wb + (size_t)(r0 + lrow4) * HP + col8, &As[0][r0 * 32]);
    gl_lds16(hb + (size_t)(r0 + lrow4) * bstride + col8, &Bs[0][r0 * 32]);
  }
  __syncthreads();

  for (int kt = 0; kt < HP / 32; ++kt) {
    const int cur = kt & 1;
    if (kt + 1 < HP / 32) {
      const int nk = (kt + 1) * 32;
#pragma unroll
      for (int i2 = 0; i2 < 2; i2++) {
        int r0 = wave * 32 + i2 * 16;
        gl_lds16(Wb + (size_t)(r0 + lrow4) * HP + nk + col8, &As[cur ^ 1][r0 * 32]);
        gl_lds16(hb + (size_t)(r0 + lrow4) * bstride + nk + col8,
                 &Bs[cur ^ 1][r0 * 32]);
      }
    }
    half8 af[4], bf8[4];
#pragma unroll
    for (int i = 0; i < 4; i++) {
      af[i] = *(const half8*)&As[cur][(wm * 64 + i * 16 + lr) * 32 + kq];
      bf8[i] = *(const half8*)&Bs[cur][(wn * 64 + i * 16 + lr) * 32 + kq];
    }
#pragma unroll
    for (int i = 0; i < 4; i++)
#pragma unroll
      for (int j = 0; j < 4; j++)
        acc[i][j] = __builtin_amdgcn_mfma_f32_16x16x32_f16(af[i], bf8[j],
                                                           acc[i][j], 0, 0, 0);
    __syncthreads();
  }
  // loop's final barrier: all LDS reads done -> tile reuse safe

  // Gate epilogue -> stage hn into LDS tile [jh_local][b_local], stride 136.
#pragma unroll
  for (int i = 0; i < 4; i++) {
    const int jl = wm * 16 + i * 4 + lq;  // 0..31
    const int jh = wt * 32 + jl;
    float4 b4 = {0.f, 0.f, 0.f, 0.f};
    if (jh < H_) b4 = *(const float4*)&bias[d * ND + 4 * jh];
#pragma unroll
    for (int j = 0; j < 4; j++) {
      const int bl = wn * 64 + j * 16 + lr;  // 0..127
      const int b = bt * 128 + bl;
      f16 hnv = (f16)0.f;
      if (jh < H_) {
        const half4 x4 = xz4[((size_t)d * HP + jh) * B_ + b];
        float zi = acc[i][j][0] + b4.x + (float)x4[0];
        float zf = acc[i][j][1] + b4.y + (float)x4[1];
        float zg = acc[i][j][2] + b4.z + (float)x4[2];
        float zo = acc[i][j][3] + b4.w + (float)x4[3];
        const size_t cidx = ((size_t)d * H_ + jh) * B_ + b;
        float co = c[cidx];
        float cn = sigmoid_(zf) * co + sigmoid_(zi) * tanh_fast(zg);
        float hn = sigmoid_(zo) * tanh_fast(cn);
        c[cidx] = cn;
        hnv = (f16)hn;
      }
      tile[jl * 136 + bl] = hnv;
    }
  }
  __syncthreads();

  // Coalesced write-out: thread -> (b_local = tid>>1, 16-jh half = tid&1).
  {
    const int bl = tid >> 1, jhalf = tid & 1;
    const int b = bt * 128 + bl;
    const int jh0 = wt * 32 + jhalf * 16;
    if (jh0 < H_) {
      f16 vals[16];
#pragma unroll
      for (int jj = 0; jj < 16; jj++)
        vals[jj] = tile[(jhalf * 16 + jj) * 136 + bl];
      half8 v0, v1;
#pragma unroll
      for (int r = 0; r < 8; r++) { v0[r] = vals[r]; v1[r] = vals[8 + r]; }
      f16* sdst = hs + ((size_t)d * B_ + b) * SB2 + t * TR + jh0;
      *(half8*)sdst = v0;
      *(half8*)(sdst + 8) = v1;
    }
  }
}

// ---------------------------------------------------------------------------
// attn1: alpha[b][t] = softmax_t( sum_h tanh(hs0+hs1) * conv_w[h] ).
// ---------------------------------------------------------------------------
__global__ __launch_bounds__(256) void attn1(const f16* __restrict__ hs,
                                             const float* __restrict__ conv_w,
                                             float* __restrict__ alpha_g) {
  __shared__ float cw[TR];
  __shared__ float red[48];
  const int b = blockIdx.x, tid = threadIdx.x;
  const int wave = tid >> 6, lane = tid & 63;
  for (int k = tid; k < TR; k += 256) cw[k] = (k < H_) ? conv_w[k] : 0.f;
  __syncthreads();

  const half4* s0 = (const half4*)(hs + (size_t)b * SB2);
  const half4* s1 = (const half4*)(hs + (size_t)(B_ + b) * SB2);
  for (int t = wave; t < T_; t += 4) {
    const int base = t * (TR / 4);
    float p = 0.f;
    {
      half4 a = s0[base + lane], cc = s1[base + lane];
#pragma unroll
      for (int r = 0; r < 4; r++)
        p += tanh_fast((float)a[r] + (float)cc[r]) * cw[lane * 4 + r];
    }
    if (lane < 12) {
      half4 a = s0[base + 64 + lane], cc = s1[base + 64 + lane];
#pragma unroll
      for (int r = 0; r < 4; r++)
        p += tanh_fast((float)a[r] + (float)cc[r]) * cw[256 + lane * 4 + r];
    }
#pragma unroll
    for (int o = 32; o; o >>= 1) p += __shfl_down(p, o);
    if (lane == 0) red[t] = p;
  }
  __syncthreads();
  if (tid < 64) {
    float a = (tid < T_) ? red[tid] : -1e30f;
    float mx = a;
#pragma unroll
    for (int o = 32; o; o >>= 1) mx = fmaxf(mx, __shfl_xor(mx, o));
    float e = (tid < T_) ? __expf(a - mx) : 0.f;
    float s = e;
#pragma unroll
    for (int o = 32; o; o >>= 1) s += __shfl_xor(s, o);
    if (tid < T_) alpha_g[(size_t)b * 44 + tid] = e / s;
  }
}

// ---------------------------------------------------------------------------
// attn2: r = sum_t hsum*alpha; hstar = tanh(r); FC logits; softmax.
// ---------------------------------------------------------------------------
__global__ __launch_bounds__(256) void attn2(const f16* __restrict__ hs,
                                             const float* __restrict__ alpha_g,
                                             const float* __restrict__ fc_w,
                                             const float* __restrict__ fc_b,
                                             float* __restrict__ out) {
  __shared__ float al[T_];
  __shared__ float hstar[TR];
  __shared__ float lg[NC_];
  const int b = blockIdx.x, tid = threadIdx.x;
  if (tid < T_) al[tid] = alpha_g[(size_t)b * 44 + tid];
  __syncthreads();

  const f16* s0 = hs + (size_t)b * SB2;
  const f16* s1 = hs + (size_t)(B_ + b) * SB2;
  float r0 = 0.f, r1 = 0.f;
  for (int t = 0; t < T_; t++) {
    const float a = al[t];
    r0 += ((float)s0[t * TR + tid] + (float)s1[t * TR + tid]) * a;
    if (tid < 48)
      r1 += ((float)s0[t * TR + 256 + tid] + (float)s1[t * TR + 256 + tid]) * a;
  }
  hstar[tid] = tanh_fast(r0);
  if (tid < 48) hstar[256 + tid] = tanh_fast(r1);
  __syncthreads();

  const int wave = tid >> 6, lane = tid & 63;
  for (int cls = wave; cls < NC_; cls += 4) {
    float p = 0.f;
    for (int k = lane; k < H_; k += 64) p += hstar[k] * fc_w[(size_t)cls * H_ + k];
#pragma unroll
    for (int o = 32; o; o >>= 1) p += __shfl_down(p, o);
    if (lane == 0) lg[cls] = p + fc_b[cls];
  }
  __syncthreads();
  if (tid < 64) {
    float a0 = (tid < 40) ? lg[tid] : -1e30f;
    float a1 = (tid < 40) ? lg[tid + 40] : -1e30f;
    float mx = fmaxf(a0, a1);
#pragma unroll
    for (int o = 32; o; o >>= 1) mx = fmaxf(mx, __shfl_xor(mx, o));
    float e0 = (tid < 40) ? __expf(a0 - mx) : 0.f;
    float e1 = (tid < 40) ? __expf(a1 - mx) : 0.f;
    float s = e0 + e1;
#pragma unroll
    for (int o = 32; o; o >>= 1) s += __shfl_xor(s, o);
    if (tid < 40) {
      out[(size_t)b * NC_ + tid] = e0 / s;
      out[(size_t)b * NC_ + tid + 40] = e1 / s;
    }
  }
}

// ---------------------------------------------------------------------------
extern "C" void kernel_launch(void* const* d_in, const int* in_sizes, int n_in,
                              void* d_out, int out_size, void* d_ws, size_t ws_size,
                              hipStream_t stream) {
  const float* x      = (const float*)d_in[0];
  const float* w_ih   = (const float*)d_in[1];
  const float* w_hh   = (const float*)d_in[2];
  const float* b_ih   = (const float*)d_in[3];
  const float* b_hh   = (const float*)d_in[4];
  const float* conv_w = (const float*)d_in[5];
  const float* fc_w   = (const float*)d_in[6];
  const float* fc_b   = (const float*)d_in[7];
  float* out = (float*)d_out;

  // Workspace carve (~431 MB)
  char* p = (char*)d_ws;
  f16* Wih = (f16*)p;   p += (size_t)NDD * HP * sizeof(f16);
  f16* Whh = (f16*)p;   p += (size_t)NDD * HP * sizeof(f16);
  float* bias = (float*)p; p += (size_t)NDD * sizeof(float);
  p = (char*)(((uintptr_t)p + 255) & ~(uintptr_t)255);
  f16* xT = (f16*)p;    p += (size_t)T_ * B_ * HP * sizeof(f16);    // 112.7 MB
  float* c = (float*)p; p += (size_t)2 * B_ * H_ * sizeof(float);   // 9.8 MB
  f16* zbuf = (f16*)p;  p += ((size_t)2 * B_ * TR + 64) * sizeof(f16); // 5.0 MB
  f16* hs = (f16*)p;    p += ((size_t)2 * B_ * SB2 + 64) * sizeof(f16); // 214.2 MB
  half4* xz = (half4*)p; p += (size_t)XZC * 2 * HP * B_ * sizeof(half4); // 83.9 MB
  float* alpha_g = (float*)p; p += (size_t)B_ * 44 * sizeof(float);

  hipMemsetAsync(zbuf, 0, ((size_t)2 * B_ * TR + 64) * sizeof(f16), stream);
  hipMemsetAsync(c, 0, (size_t)2 * B_ * H_ * sizeof(float), stream);

  prep_weights<<<(2 * NDD * HP + 255) / 256, 256, 0, stream>>>(
      w_ih, w_hh, b_ih, b_hh, Wih, Whh, bias);
  prep_xT<<<dim3(B_, 5), 256, 0, stream>>>(x, xT);

  const size_t xzslab = (size_t)2 * HP * B_;   // half4 units per t_local
  int t0 = 0;
  while (t0 < T_) {
    int cn = (T_ - t0 < XZC) ? (T_ - t0) : XZC;
    xz_gemm<<<dim3(cn * 32, 20), 256, 0, stream>>>(
        xT + (size_t)t0 * B_ * HP, Wih, xz);
    for (int tt = 0; tt < cn; ++tt) {
      int t = t0 + tt;
      const f16* hp = (t == 0) ? zbuf : (hs + (size_t)(t - 1) * TR);
      long bs = (t == 0) ? TR : SB2;
      long ds = (t == 0) ? (long)B_ * TR : (long)B_ * SB2;
      lstm_step<<<dim3(10, 32, 2), 256, 0, stream>>>(
          hp, bs, ds, c, Whh, bias, xz + (size_t)tt * xzslab, hs, t);
    }
    t0 += cn;
  }

  attn1<<<B_, 256, 0, stream>>>(hs, conv_w, alpha_g);
  attn2<<<B_, 256, 0, stream>>>(hs, alpha_g, fc_w, fc_b, out);
}